// Round 1
// baseline (871.284 us; speedup 1.0000x reference)
//
#include <hip/hip_runtime.h>

// ---------------------------------------------------------------------------
// CombinedModel: 3x relu-LSTM (keypoint) + tanh-LSTM + GRU (img) + dense heads
// Strategy:
//   - Big input projections via split-bf16 MFMA GEMM (hi/lo decomposition,
//     3 MFMAs per tile-pair -> ~fp32 accuracy at bf16 matrix-core rate).
//   - Recurrences: one block per batch row (rows independent -> no grid sync),
//     recurrent weight columns register-resident, h broadcast via LDS.
// ---------------------------------------------------------------------------

typedef short bf16x8 __attribute__((ext_vector_type(8)));
typedef float f32x4 __attribute__((ext_vector_type(4)));

__device__ __forceinline__ unsigned f2bf(float x) {
    unsigned u = __float_as_uint(x);
    return (u + 0x7FFFu + ((u >> 16) & 1u)) >> 16;   // RNE; inputs finite
}
__device__ __forceinline__ float bf2f(unsigned b) { return __uint_as_float(b << 16); }
__device__ __forceinline__ float sigmoidf_(float x) { return 1.f / (1.f + __expf(-x)); }

// ---------------------------------------------------------------------------
// Weight pre-split: W[K,N] f32 -> blocked bf16 hi/lo [kt][n][40] (kk 0..31 data,
// zero-padded for kk>=32 or k>=K so the GEMM needs no B-side guards).
// ---------------------------------------------------------------------------
template<int K, int N>
__device__ __forceinline__ void split_w(const float* __restrict__ W,
                                        unsigned short* __restrict__ hi,
                                        unsigned short* __restrict__ lo, int item) {
    int kt = item / N;
    int n  = item % N;
    unsigned uh[20], ul[20];
#pragma unroll
    for (int p = 0; p < 20; p++) {
        unsigned h2[2], l2[2];
#pragma unroll
        for (int e = 0; e < 2; e++) {
            int kk = p * 2 + e;
            int k  = kt * 32 + kk;
            float x = (kk < 32 && k < K) ? W[(size_t)k * N + n] : 0.f;
            unsigned hb = f2bf(x);
            h2[e] = hb;
            l2[e] = f2bf(x - bf2f(hb));
        }
        uh[p] = h2[0] | (h2[1] << 16);
        ul[p] = l2[0] | (l2[1] << 16);
    }
    size_t off = (size_t)(kt * N + n) * 40;  // ushort idx; *2B = 80B -> 16B aligned
    uint4* dh = (uint4*)(hi + off);
    uint4* dl = (uint4*)(lo + off);
#pragma unroll
    for (int c = 0; c < 5; c++) {
        uint4 v; v.x = uh[c*4]; v.y = uh[c*4+1]; v.z = uh[c*4+2]; v.w = uh[c*4+3];
        dh[c] = v;
        uint4 u; u.x = ul[c*4]; u.y = ul[c*4+1]; u.z = ul[c*4+2]; u.w = ul[c*4+3];
        dl[c] = u;
    }
}

__global__ __launch_bounds__(256) void split_all(
    const float* kW1x, const float* iWx, const float* kW2x, const float* kW3x,
    unsigned short* w1h, unsigned short* w1l, unsigned short* wih, unsigned short* wil,
    unsigned short* w2h, unsigned short* w2l, unsigned short* w3h, unsigned short* w3l) {
    int wid = blockIdx.x * 256 + threadIdx.x;
    // ranges: W1: 52*256=13312 | Wimg: 64*256=16384 | W2: 2*512=1024 | W3: 4*256=1024
    if (wid < 13312)       split_w<1662, 256>(kW1x, w1h, w1l, wid);
    else if (wid < 29696)  split_w<2048, 256>(iWx,  wih, wil, wid - 13312);
    else if (wid < 30720)  split_w<64,   512>(kW2x, w2h, w2l, wid - 29696);
    else if (wid < 31744)  split_w<128,  256>(kW3x, w3h, w3l, wid - 30720);
}

// ---------------------------------------------------------------------------
// Split-bf16 MFMA GEMM: out[16384,Nfull] = A[16384,Kreal] @ W + bias
// Block: 256 thr = 4 waves, tile 64 rows x 256 cols; wave -> 64 cols (4x4 MFMA
// tiles of 16x16x32). grid.x = 256 * (Nfull/256).
// ---------------------------------------------------------------------------
__global__ __launch_bounds__(256) void gemm_split_k(
    const float* __restrict__ A, const unsigned short* __restrict__ Whi,
    const unsigned short* __restrict__ Wlo, const float* __restrict__ bias,
    float* __restrict__ out, int Kreal, int Kt, int Nfull) {
    const int bid = blockIdx.x;
    const int mb  = bid & 255;
    const int nh  = bid >> 8;
    const int m0  = mb * 64;
    const int n0  = nh * 256;
    const int tid = threadIdx.x;
    const int lane = tid & 63;
    const int wv   = tid >> 6;
    const int l15  = lane & 15;
    const int q    = lane >> 4;

    __shared__ unsigned short Ah[64 * 40], Al[64 * 40];     // rows padded to 40
    __shared__ unsigned short Bh[256 * 40], Bl[256 * 40];

    f32x4 acc[4][4];
#pragma unroll
    for (int i = 0; i < 4; i++)
#pragma unroll
        for (int j = 0; j < 4; j++) acc[i][j] = (f32x4){0.f, 0.f, 0.f, 0.f};

    for (int kt = 0; kt < Kt; kt++) {
        __syncthreads();
        // ---- stage A (fp32 -> hi/lo bf16), 64 rows x 32 k ----
#pragma unroll
        for (int it = 0; it < 2; it++) {
            int item = tid + it * 256;
            int row = item >> 3, kg = item & 7;
            int gk = kt * 32 + kg * 4;
            const float* ap = A + (size_t)(m0 + row) * Kreal + gk;
            float x0, x1, x2, x3;
            if (gk + 4 <= Kreal) {       // rows are 8B-aligned (K even) -> float2
                float2 p0 = *(const float2*)ap;
                float2 p1 = *(const float2*)(ap + 2);
                x0 = p0.x; x1 = p0.y; x2 = p1.x; x3 = p1.y;
            } else {
                x0 = (gk + 0 < Kreal) ? ap[0] : 0.f;
                x1 = (gk + 1 < Kreal) ? ap[1] : 0.f;
                x2 = (gk + 2 < Kreal) ? ap[2] : 0.f;
                x3 = (gk + 3 < Kreal) ? ap[3] : 0.f;
            }
            unsigned h0 = f2bf(x0), h1 = f2bf(x1), h2 = f2bf(x2), h3 = f2bf(x3);
            unsigned l0 = f2bf(x0 - bf2f(h0)), l1 = f2bf(x1 - bf2f(h1));
            unsigned l2 = f2bf(x2 - bf2f(h2)), l3 = f2bf(x3 - bf2f(h3));
            uint2 vh; vh.x = h0 | (h1 << 16); vh.y = h2 | (h3 << 16);
            uint2 vl; vl.x = l0 | (l1 << 16); vl.y = l2 | (l3 << 16);
            *(uint2*)&Ah[row * 40 + kg * 4] = vh;
            *(uint2*)&Al[row * 40 + kg * 4] = vl;
        }
        // ---- stage B (pre-split, already in LDS image layout) ----
        {
            const uint4* sh = (const uint4*)(Whi + ((size_t)kt * Nfull + n0) * 40);
            const uint4* sl = (const uint4*)(Wlo + ((size_t)kt * Nfull + n0) * 40);
            uint4* dh = (uint4*)Bh; uint4* dl = (uint4*)Bl;
#pragma unroll
            for (int r = 0; r < 5; r++) {
                dh[tid + r * 256] = sh[tid + r * 256];
                dl[tid + r * 256] = sl[tid + r * 256];
            }
        }
        __syncthreads();
        // ---- fragments + MFMA ----
        bf16x8 a_h[4], a_l[4], b_h[4], b_l[4];
#pragma unroll
        for (int mt = 0; mt < 4; mt++) {
            int o = (mt * 16 + l15) * 40 + q * 8;   // 16B aligned (row*80 + q*16)
            a_h[mt] = *(const bf16x8*)&Ah[o];
            a_l[mt] = *(const bf16x8*)&Al[o];
        }
#pragma unroll
        for (int nt = 0; nt < 4; nt++) {
            int o = (wv * 64 + nt * 16 + l15) * 40 + q * 8;
            b_h[nt] = *(const bf16x8*)&Bh[o];
            b_l[nt] = *(const bf16x8*)&Bl[o];
        }
#pragma unroll
        for (int mt = 0; mt < 4; mt++)
#pragma unroll
            for (int nt = 0; nt < 4; nt++) {
                acc[mt][nt] = __builtin_amdgcn_mfma_f32_16x16x32_bf16(a_h[mt], b_h[nt], acc[mt][nt], 0, 0, 0);
                acc[mt][nt] = __builtin_amdgcn_mfma_f32_16x16x32_bf16(a_h[mt], b_l[nt], acc[mt][nt], 0, 0, 0);
                acc[mt][nt] = __builtin_amdgcn_mfma_f32_16x16x32_bf16(a_l[mt], b_h[nt], acc[mt][nt], 0, 0, 0);
            }
    }
    // ---- epilogue: C/D layout col=lane&15, row=quad*4+reg ----
#pragma unroll
    for (int nt = 0; nt < 4; nt++) {
        int gcol = n0 + wv * 64 + nt * 16 + l15;
        float bv = bias[gcol];
#pragma unroll
        for (int mt = 0; mt < 4; mt++)
#pragma unroll
            for (int r = 0; r < 4; r++) {
                int grow = m0 + mt * 16 + q * 4 + r;
                out[(size_t)grow * Nfull + gcol] = acc[mt][nt][r] + bv;
            }
    }
}

// ---------------------------------------------------------------------------
// LSTM with H=64, G=256 (dual-config so keypoint-LSTM1 + img-LSTM fuse into one
// launch). One block per batch row; thread g owns gate g with Wh[:,g] in VGPRs.
// act: 0 = relu, 1 = tanh. xz already contains x@Wx + b.
// ---------------------------------------------------------------------------
__global__ __launch_bounds__(256) void lstm_h64(
    int nA,
    const float* __restrict__ xzA, const float* __restrict__ WhA, float* __restrict__ hA, int actA,
    const float* __restrict__ xzB, const float* __restrict__ WhB, float* __restrict__ hB, int actB) {
    int bid = blockIdx.x;
    bool sec = bid >= nA;
    int b = sec ? bid - nA : bid;
    const float* xz = sec ? xzB : xzA;
    const float* Wh = sec ? WhB : WhA;
    float* hout     = sec ? hB  : hA;
    int act         = sec ? actB : actA;

    int g = threadIdx.x;
    float w[64];
#pragma unroll
    for (int k = 0; k < 64; k++) w[k] = Wh[k * 256 + g];

    __shared__ alignas(16) float hs[64];
    __shared__ float za[256];
    if (g < 64) hs[g] = 0.f;
    float c = 0.f;
    __syncthreads();

    const float* xzr = xz + (size_t)b * 64 * 256;
    float* hr = hout + (size_t)b * 64 * 64;
    bool isc = (g >= 128) && (g < 192);
    for (int t = 0; t < 64; t++) {
        float z = xzr[t * 256 + g];
#pragma unroll
        for (int kk = 0; kk < 16; kk++) {
            float4 h4 = *(const float4*)&hs[kk * 4];   // broadcast reads
            z = fmaf(h4.x, w[kk * 4 + 0], z);
            z = fmaf(h4.y, w[kk * 4 + 1], z);
            z = fmaf(h4.z, w[kk * 4 + 2], z);
            z = fmaf(h4.w, w[kk * 4 + 3], z);
        }
        float a;
        if (isc) a = (act == 0) ? fmaxf(z, 0.f) : tanhf(z);
        else     a = sigmoidf_(z);
        za[g] = a;
        __syncthreads();
        if (g < 64) {
            float iv = za[g], fv = za[64 + g], cd = za[128 + g], ov = za[192 + g];
            c = fmaf(fv, c, iv * cd);
            float ca = (act == 0) ? fmaxf(c, 0.f) : tanhf(c);
            float h = ov * ca;
            hs[g] = h;
            hr[t * 64 + g] = h;
        }
        __syncthreads();
    }
}

// ---------------------------------------------------------------------------
// LSTM with H=128, G=512 (keypoint layer 2, relu). 512 threads/block.
// ---------------------------------------------------------------------------
__global__ __launch_bounds__(512, 2) void lstm_h128(
    const float* __restrict__ xz, const float* __restrict__ Wh, float* __restrict__ hout) {
    int b = blockIdx.x;
    int g = threadIdx.x;
    float w[128];
#pragma unroll
    for (int k = 0; k < 128; k++) w[k] = Wh[k * 512 + g];

    __shared__ alignas(16) float hs[128];
    __shared__ float za[512];
    if (g < 128) hs[g] = 0.f;
    float c = 0.f;
    __syncthreads();

    const float* xzr = xz + (size_t)b * 64 * 512;
    float* hr = hout + (size_t)b * 64 * 128;
    bool isc = (g >= 256) && (g < 384);
    for (int t = 0; t < 64; t++) {
        float z = xzr[t * 512 + g];
#pragma unroll
        for (int kk = 0; kk < 32; kk++) {
            float4 h4 = *(const float4*)&hs[kk * 4];
            z = fmaf(h4.x, w[kk * 4 + 0], z);
            z = fmaf(h4.y, w[kk * 4 + 1], z);
            z = fmaf(h4.z, w[kk * 4 + 2], z);
            z = fmaf(h4.w, w[kk * 4 + 3], z);
        }
        float a = isc ? fmaxf(z, 0.f) : sigmoidf_(z);
        za[g] = a;
        __syncthreads();
        if (g < 128) {
            float iv = za[g], fv = za[128 + g], cd = za[256 + g], ov = za[384 + g];
            c = fmaf(fv, c, iv * cd);
            float h = ov * fmaxf(c, 0.f);
            hs[g] = h;
            hr[t * 128 + g] = h;
        }
        __syncthreads();
    }
}

// ---------------------------------------------------------------------------
// GRU (reset_after=True), H=8, G=24, input = img-LSTM hidden seq [B*T,64].
// 4 rows per 256-thread block; gate order z,r,h.
// ---------------------------------------------------------------------------
__global__ __launch_bounds__(256) void gru_kernel(
    const float* __restrict__ hsimg, const float* __restrict__ gWx,
    const float* __restrict__ gWh, const float* __restrict__ gb,
    float* __restrict__ glast) {
    int tid = threadIdx.x;
    int rr = tid >> 6, qq = tid & 63;
    int b = blockIdx.x * 4 + rr;
    float wx[64], wh[8], b0 = 0.f, b1 = 0.f;
    if (qq < 24) {
#pragma unroll
        for (int k = 0; k < 64; k++) wx[k] = gWx[k * 24 + qq];
#pragma unroll
        for (int k = 0; k < 8; k++)  wh[k] = gWh[k * 24 + qq];
        b0 = gb[qq]; b1 = gb[24 + qq];
    }
    __shared__ alignas(16) float hld[4][64];
    __shared__ float hh[4][8];
    __shared__ float zx[4][24], zr[4][24];
    if (qq < 8) hh[rr][qq] = 0.f;
    __syncthreads();
    const float* hb = hsimg + (size_t)b * 64 * 64;
    for (int t = 0; t < 64; t++) {
        hld[rr][qq] = hb[t * 64 + qq];
        __syncthreads();
        if (qq < 24) {
            float sx = b0;
#pragma unroll
            for (int kk = 0; kk < 16; kk++) {
                float4 h4 = *(const float4*)&hld[rr][kk * 4];
                sx = fmaf(h4.x, wx[kk * 4 + 0], sx);
                sx = fmaf(h4.y, wx[kk * 4 + 1], sx);
                sx = fmaf(h4.z, wx[kk * 4 + 2], sx);
                sx = fmaf(h4.w, wx[kk * 4 + 3], sx);
            }
            float sr = b1;
#pragma unroll
            for (int k = 0; k < 8; k++) sr = fmaf(hh[rr][k], wh[k], sr);
            zx[rr][qq] = sx; zr[rr][qq] = sr;
        }
        __syncthreads();
        if (qq < 8) {
            float zz = sigmoidf_(zx[rr][qq] + zr[rr][qq]);
            float rv = sigmoidf_(zx[rr][8 + qq] + zr[rr][8 + qq]);
            float hc = tanhf(zx[rr][16 + qq] + rv * zr[rr][16 + qq]);
            float hn = zz * hh[rr][qq] + (1.f - zz) * hc;
            hh[rr][qq] = hn;
            if (t == 63) glast[b * 8 + qq] = hn;
        }
        __syncthreads();
    }
}

// ---------------------------------------------------------------------------
// Dense heads + concat + final dense + softmax. One thread per batch row.
// ---------------------------------------------------------------------------
__global__ __launch_bounds__(256) void final_head(
    const float* __restrict__ h3seq, const float* __restrict__ glast,
    const float* __restrict__ kD1w, const float* __restrict__ kD1b,
    const float* __restrict__ kD2w, const float* __restrict__ kD2b,
    const float* __restrict__ iDw,  const float* __restrict__ iDb,
    const float* __restrict__ fW,   const float* __restrict__ fb,
    float* __restrict__ outp) {
    int b = threadIdx.x;
    float h3[64];
#pragma unroll
    for (int k = 0; k < 64; k++) h3[k] = h3seq[((size_t)b * 64 + 63) * 64 + k];
    float d1[64];
#pragma unroll
    for (int j = 0; j < 64; j++) {
        float s = kD1b[j];
#pragma unroll
        for (int k = 0; k < 64; k++) s = fmaf(h3[k], kD1w[k * 64 + j], s);
        d1[j] = fmaxf(s, 0.f);
    }
    float d2[32];
#pragma unroll
    for (int j = 0; j < 32; j++) {
        float s = kD2b[j];
#pragma unroll
        for (int k = 0; k < 64; k++) s = fmaf(d1[k], kD2w[k * 32 + j], s);
        d2[j] = fmaxf(s, 0.f);
    }
    float gi[8];
#pragma unroll
    for (int k = 0; k < 8; k++) gi[k] = glast[b * 8 + k];
    float io[8];
#pragma unroll
    for (int j = 0; j < 8; j++) {
        float s = iDb[j];
#pragma unroll
        for (int k = 0; k < 8; k++) s = fmaf(gi[k], iDw[k * 8 + j], s);
        io[j] = fmaxf(s, 0.f);
    }
    float lg[10];
#pragma unroll
    for (int j = 0; j < 10; j++) {
        float s = fb[j];
#pragma unroll
        for (int k = 0; k < 8; k++)  s = fmaf(io[k], fW[k * 10 + j], s);
#pragma unroll
        for (int k = 0; k < 32; k++) s = fmaf(d2[k], fW[(8 + k) * 10 + j], s);
        lg[j] = s;
    }
    float mx = lg[0];
#pragma unroll
    for (int j = 1; j < 10; j++) mx = fmaxf(mx, lg[j]);
    float den = 0.f, ex[10];
#pragma unroll
    for (int j = 0; j < 10; j++) { ex[j] = __expf(lg[j] - mx); den += ex[j]; }
    float inv = 1.f / den;
#pragma unroll
    for (int j = 0; j < 10; j++) outp[b * 10 + j] = ex[j] * inv;
}

// ---------------------------------------------------------------------------
extern "C" void kernel_launch(void* const* d_in, const int* in_sizes, int n_in,
                              void* d_out, int out_size, void* d_ws, size_t ws_size,
                              hipStream_t stream) {
    const float* keypoint = (const float*)d_in[0];
    const float* img      = (const float*)d_in[1];
    const float* kW1x = (const float*)d_in[2];
    const float* kW1h = (const float*)d_in[3];
    const float* kb1  = (const float*)d_in[4];
    const float* kW2x = (const float*)d_in[5];
    const float* kW2h = (const float*)d_in[6];
    const float* kb2  = (const float*)d_in[7];
    const float* kW3x = (const float*)d_in[8];
    const float* kW3h = (const float*)d_in[9];
    const float* kb3  = (const float*)d_in[10];
    const float* kD1w = (const float*)d_in[11];
    const float* kD1b = (const float*)d_in[12];
    const float* kD2w = (const float*)d_in[13];
    const float* kD2b = (const float*)d_in[14];
    const float* iWx  = (const float*)d_in[15];
    const float* iWh  = (const float*)d_in[16];
    const float* ib   = (const float*)d_in[17];
    const float* gWx  = (const float*)d_in[18];
    const float* gWh  = (const float*)d_in[19];
    const float* gb   = (const float*)d_in[20];
    const float* iDw  = (const float*)d_in[21];
    const float* iDb  = (const float*)d_in[22];
    const float* fW   = (const float*)d_in[23];
    const float* fb   = (const float*)d_in[24];
    float* outp = (float*)d_out;

    char* ws = (char*)d_ws;
    size_t off = 0;
    float* xz1   = (float*)(ws + off); off += (size_t)16384 * 256 * 4;  // also xz3 later
    float* xz2b  = (float*)(ws + off); off += (size_t)16384 * 512 * 4;  // xz_img then xz2
    float* h1seq = (float*)(ws + off); off += (size_t)16384 * 64 * 4;   // also h3seq later
    float* h2seq = (float*)(ws + off); off += (size_t)16384 * 128 * 4;
    float* hsimg = (float*)(ws + off); off += (size_t)16384 * 64 * 4;
    float* glast = (float*)(ws + off); off += (size_t)256 * 8 * 4;
    unsigned short* w1h = (unsigned short*)(ws + off); off += (size_t)52 * 256 * 40 * 2;
    unsigned short* w1l = (unsigned short*)(ws + off); off += (size_t)52 * 256 * 40 * 2;
    unsigned short* wih = (unsigned short*)(ws + off); off += (size_t)64 * 256 * 40 * 2;
    unsigned short* wil = (unsigned short*)(ws + off); off += (size_t)64 * 256 * 40 * 2;
    unsigned short* w2h = (unsigned short*)(ws + off); off += (size_t)2 * 512 * 40 * 2;
    unsigned short* w2l = (unsigned short*)(ws + off); off += (size_t)2 * 512 * 40 * 2;
    unsigned short* w3h = (unsigned short*)(ws + off); off += (size_t)4 * 256 * 40 * 2;
    unsigned short* w3l = (unsigned short*)(ws + off); off += (size_t)4 * 256 * 40 * 2;
    float* xz_img = xz2b;         // [16384,256], overwritten by xz2 after use
    float* xz3    = xz1;          // reuse after LSTM1 consumed xz1
    float* h3seq  = h1seq;        // reuse after xz2 GEMM consumed h1seq

    // 1. pre-split projection weights to blocked bf16 hi/lo
    split_all<<<124, 256, 0, stream>>>(kW1x, iWx, kW2x, kW3x,
                                       w1h, w1l, wih, wil, w2h, w2l, w3h, w3l);
    // 2. xz1 = keypoint @ kW1x + kb1
    gemm_split_k<<<256, 256, 0, stream>>>(keypoint, w1h, w1l, kb1, xz1, 1662, 52, 256);
    // 3. xz_img = img @ iWx + ib
    gemm_split_k<<<256, 256, 0, stream>>>(img, wih, wil, ib, xz_img, 2048, 64, 256);
    // 4. LSTM1 (relu) + img LSTM (tanh), fused
    lstm_h64<<<512, 256, 0, stream>>>(256, xz1, kW1h, h1seq, 0, xz_img, iWh, hsimg, 1);
    // 5. xz2 = h1seq @ kW2x + kb2
    gemm_split_k<<<512, 256, 0, stream>>>(h1seq, w2h, w2l, kb2, xz2b, 64, 2, 512);
    // 6. LSTM2 (relu)
    lstm_h128<<<256, 512, 0, stream>>>(xz2b, kW2h, h2seq);
    // 7. xz3 = h2seq @ kW3x + kb3
    gemm_split_k<<<256, 256, 0, stream>>>(h2seq, w3h, w3l, kb3, xz3, 128, 4, 256);
    // 8. LSTM3 (relu), write full seq (buffer reused), last step read by head
    lstm_h64<<<256, 256, 0, stream>>>(256, xz3, kW3h, h3seq, 0, xz3, kW3h, h3seq, 0);
    // 9. GRU over img LSTM hidden seq
    gru_kernel<<<64, 256, 0, stream>>>(hsimg, gWx, gWh, gb, glast);
    // 10. dense heads + softmax
    final_head<<<1, 256, 0, stream>>>(h3seq, glast, kD1w, kD1b, kD2w, kD2b,
                                      iDw, iDb, fW, fb, outp);
    (void)in_sizes; (void)n_in; (void)out_size; (void)ws_size;
}

// Round 2
// 754.639 us; speedup vs baseline: 1.1546x; 1.1546x over previous
//
#include <hip/hip_runtime.h>

// ---------------------------------------------------------------------------
// CombinedModel: 3x relu-LSTM (keypoint) + tanh-LSTM + GRU (img) + heads.
//   GEMMs: split-bf16 MFMA (hi/lo, 3 MFMA per tile-pair ~= fp32 accuracy).
//     B register-direct from pre-split global [kt][n][32] (no LDS, no conflicts)
//     A LDS-staged hi/lo, double-buffered, ONE barrier per kt.
//     split-K=2 -> 2 partial buffers summed by the consuming LSTM (no atomics).
//   Recurrences: block per batch row, weights in VGPRs, 4-way FMA chains,
//     xz prefetch, fast tanh. GRU: 1 wave/row, shuffle-based, barrier-free.
// ---------------------------------------------------------------------------

typedef short bf16x8 __attribute__((ext_vector_type(8)));
typedef float f32x4 __attribute__((ext_vector_type(4)));

__device__ __forceinline__ unsigned f2bf(float x) {
    unsigned u = __float_as_uint(x);
    return (u + 0x7FFFu + ((u >> 16) & 1u)) >> 16;   // RNE; inputs finite
}
__device__ __forceinline__ float bf2f(unsigned b) { return __uint_as_float(b << 16); }
__device__ __forceinline__ float sigmoidf_(float x) { return 1.f / (1.f + __expf(-x)); }
__device__ __forceinline__ float tanhf_(float x) {
    float e = __expf(2.f * x);           // x->+inf: 1-0=1; x->-inf: 1-2=-1
    return 1.f - 2.f / (e + 1.f);
}

// ---------------------------------------------------------------------------
// Weight pre-split: W[K,N] f32 -> bf16 hi/lo, blocked [kt][n][32] (fragment-
// native: wave B-frag load = 1KB contiguous). Zero-padded past K.
// ---------------------------------------------------------------------------
template<int K, int N>
__device__ __forceinline__ void split_w(const float* __restrict__ W,
                                        unsigned short* __restrict__ hi,
                                        unsigned short* __restrict__ lo, int item) {
    int kt = item / N;
    int n  = item % N;
    unsigned uh[16], ul[16];
#pragma unroll
    for (int p = 0; p < 16; p++) {
        unsigned h2[2], l2[2];
#pragma unroll
        for (int e = 0; e < 2; e++) {
            int k = kt * 32 + p * 2 + e;
            float x = (k < K) ? W[(size_t)k * N + n] : 0.f;
            unsigned hb = f2bf(x);
            h2[e] = hb;
            l2[e] = f2bf(x - bf2f(hb));
        }
        uh[p] = h2[0] | (h2[1] << 16);
        ul[p] = l2[0] | (l2[1] << 16);
    }
    size_t off = (size_t)(kt * N + n) * 32;   // 64B per entry -> 4x uint4
    uint4* dh = (uint4*)(hi + off);
    uint4* dl = (uint4*)(lo + off);
#pragma unroll
    for (int c = 0; c < 4; c++) {
        uint4 v; v.x = uh[c*4]; v.y = uh[c*4+1]; v.z = uh[c*4+2]; v.w = uh[c*4+3];
        dh[c] = v;
        uint4 u; u.x = ul[c*4]; u.y = ul[c*4+1]; u.z = ul[c*4+2]; u.w = ul[c*4+3];
        dl[c] = u;
    }
}

__global__ __launch_bounds__(256) void split_all(
    const float* kW1x, const float* iWx, const float* kW2x, const float* kW3x,
    unsigned short* w1h, unsigned short* w1l, unsigned short* wih, unsigned short* wil,
    unsigned short* w2h, unsigned short* w2l, unsigned short* w3h, unsigned short* w3l) {
    int wid = blockIdx.x * 256 + threadIdx.x;
    if (wid < 13312)       split_w<1662, 256>(kW1x, w1h, w1l, wid);
    else if (wid < 29696)  split_w<2048, 256>(iWx,  wih, wil, wid - 13312);
    else if (wid < 30720)  split_w<64,   512>(kW2x, w2h, w2l, wid - 29696);
    else if (wid < 31744)  split_w<128,  256>(kW3x, w3h, w3l, wid - 30720);
}

// ---------------------------------------------------------------------------
// GEMM: out = A[16384,Kreal] @ W + bias.  Block 256 thr (4 waves), tile 64x256.
// grid = (M/64, Nfull/256, ksplit).  ks==0 partial carries bias.
// ---------------------------------------------------------------------------
__global__ __launch_bounds__(256, 2) void gemm_rd(
    const float* __restrict__ A, const unsigned short* __restrict__ Bhi,
    const unsigned short* __restrict__ Blo, const float* __restrict__ bias,
    float* __restrict__ out0, float* __restrict__ out1,
    int Kreal, int Kt, int Nfull) {
    const int m0  = blockIdx.x * 64;
    const int n0  = blockIdx.y * 256;
    const int ks  = blockIdx.z;
    const int nks = gridDim.z;
    const int ktChunk = (Kt + nks - 1) / nks;
    const int kt0 = ks * ktChunk;
    const int ktEnd = min(Kt, kt0 + ktChunk);
    const int tid = threadIdx.x;
    const int lane = tid & 63;
    const int wv   = tid >> 6;
    const int l15  = lane & 15;
    const int q    = lane >> 4;

    __shared__ unsigned short Ah[2][64 * 40], Al[2][64 * 40];  // 20KB, dbuf

    f32x4 acc[4][4];
#pragma unroll
    for (int i = 0; i < 4; i++)
#pragma unroll
        for (int j = 0; j < 4; j++) acc[i][j] = (f32x4){0.f, 0.f, 0.f, 0.f};

    auto stage = [&](int kt, int buf) {
#pragma unroll
        for (int it = 0; it < 2; it++) {
            int item = tid + it * 256;
            int row = item >> 3, kg = item & 7;
            int gk = kt * 32 + kg * 4;
            const float* ap = A + (size_t)(m0 + row) * Kreal + gk;
            float x0, x1, x2, x3;
            if (gk + 4 <= Kreal) {
                float2 p0 = *(const float2*)ap;
                float2 p1 = *(const float2*)(ap + 2);
                x0 = p0.x; x1 = p0.y; x2 = p1.x; x3 = p1.y;
            } else {
                x0 = (gk + 0 < Kreal) ? ap[0] : 0.f;
                x1 = (gk + 1 < Kreal) ? ap[1] : 0.f;
                x2 = (gk + 2 < Kreal) ? ap[2] : 0.f;
                x3 = (gk + 3 < Kreal) ? ap[3] : 0.f;
            }
            unsigned h0 = f2bf(x0), h1 = f2bf(x1), h2 = f2bf(x2), h3 = f2bf(x3);
            unsigned l0 = f2bf(x0 - bf2f(h0)), l1 = f2bf(x1 - bf2f(h1));
            unsigned l2 = f2bf(x2 - bf2f(h2)), l3 = f2bf(x3 - bf2f(h3));
            uint2 vh; vh.x = h0 | (h1 << 16); vh.y = h2 | (h3 << 16);
            uint2 vl; vl.x = l0 | (l1 << 16); vl.y = l2 | (l3 << 16);
            *(uint2*)&Ah[buf][row * 40 + kg * 4] = vh;
            *(uint2*)&Al[buf][row * 40 + kg * 4] = vl;
        }
    };

    stage(kt0, 0);
    for (int kt = kt0; kt < ktEnd; kt++) {
        int b = (kt - kt0) & 1;
        // B fragments register-direct from global (L2-resident, contiguous 1KB)
        bf16x8 bh[4], bl[4];
#pragma unroll
        for (int nt = 0; nt < 4; nt++) {
            size_t boff = ((size_t)kt * Nfull + n0 + wv * 64 + nt * 16 + l15) * 32 + q * 8;
            bh[nt] = *(const bf16x8*)(Bhi + boff);
            bl[nt] = *(const bf16x8*)(Blo + boff);
        }
        __syncthreads();                       // A buf b ready
        if (kt + 1 < ktEnd) stage(kt + 1, b ^ 1);
#pragma unroll
        for (int mt = 0; mt < 4; mt++) {
            int o = (mt * 16 + l15) * 40 + q * 8;
            bf16x8 ah = *(const bf16x8*)&Ah[b][o];
            bf16x8 al = *(const bf16x8*)&Al[b][o];
#pragma unroll
            for (int nt = 0; nt < 4; nt++) {
                acc[mt][nt] = __builtin_amdgcn_mfma_f32_16x16x32_bf16(ah, bh[nt], acc[mt][nt], 0, 0, 0);
                acc[mt][nt] = __builtin_amdgcn_mfma_f32_16x16x32_bf16(ah, bl[nt], acc[mt][nt], 0, 0, 0);
                acc[mt][nt] = __builtin_amdgcn_mfma_f32_16x16x32_bf16(al, bh[nt], acc[mt][nt], 0, 0, 0);
            }
        }
    }
    float* op = (ks == 0) ? out0 : out1;
#pragma unroll
    for (int nt = 0; nt < 4; nt++) {
        int gcol = n0 + wv * 64 + nt * 16 + l15;
        float bv = (ks == 0) ? bias[gcol] : 0.f;
#pragma unroll
        for (int mt = 0; mt < 4; mt++)
#pragma unroll
            for (int r = 0; r < 4; r++) {
                int grow = m0 + mt * 16 + q * 4 + r;
                op[(size_t)grow * Nfull + gcol] = acc[mt][nt][r] + bv;
            }
    }
}

// ---------------------------------------------------------------------------
// LSTM H=64, G=256 (dual-config). xz = sum of two partials (p1 nullable).
// ---------------------------------------------------------------------------
__global__ __launch_bounds__(256) void lstm_h64(
    int nA,
    const float* __restrict__ xA0, const float* __restrict__ xA1,
    const float* __restrict__ WhA, float* __restrict__ hA, int actA,
    const float* __restrict__ xB0, const float* __restrict__ xB1,
    const float* __restrict__ WhB, float* __restrict__ hB, int actB) {
    int bid = blockIdx.x;
    bool sec = bid >= nA;
    int b = sec ? bid - nA : bid;
    const float* x0 = sec ? xB0 : xA0;
    const float* x1 = sec ? xB1 : xA1;
    const float* Wh = sec ? WhB : WhA;
    float* hout     = sec ? hB  : hA;
    int act         = sec ? actB : actA;
    bool has1 = (x1 != nullptr);

    int g = threadIdx.x;
    float w[64];
#pragma unroll
    for (int k = 0; k < 64; k++) w[k] = Wh[k * 256 + g];

    __shared__ alignas(16) float hs[64];
    __shared__ float za[256];
    if (g < 64) hs[g] = 0.f;
    float c = 0.f;
    __syncthreads();

    const float* x0r = x0 + (size_t)b * 64 * 256;
    const float* x1r = has1 ? x1 + (size_t)b * 64 * 256 : x0r;
    float* hr = hout + (size_t)b * 64 * 64;
    bool isc = (g >= 128) && (g < 192);
    float cur = x0r[g] + (has1 ? x1r[g] : 0.f);
    for (int t = 0; t < 64; t++) {
        float nxt = 0.f;                          // prefetch t+1 before chain
        if (t < 63) {
            nxt = x0r[(t + 1) * 256 + g];
            if (has1) nxt += x1r[(t + 1) * 256 + g];
        }
        float z0 = cur, z1 = 0.f, z2 = 0.f, z3 = 0.f;
#pragma unroll
        for (int kk = 0; kk < 16; kk++) {
            float4 h4 = *(const float4*)&hs[kk * 4];
            float a0 = fmaf(h4.x, w[kk * 4 + 0], fmaf(h4.y, w[kk * 4 + 1], 0.f));
            float a1 = fmaf(h4.z, w[kk * 4 + 2], fmaf(h4.w, w[kk * 4 + 3], 0.f));
            if ((kk & 3) == 0) { z0 += a0; z1 += a1; }
            else if ((kk & 3) == 1) { z2 += a0; z3 += a1; }
            else if ((kk & 3) == 2) { z0 += a0; z1 += a1; }
            else { z2 += a0; z3 += a1; }
        }
        float z = (z0 + z1) + (z2 + z3);
        float a;
        if (isc) a = (act == 0) ? fmaxf(z, 0.f) : tanhf_(z);
        else     a = sigmoidf_(z);
        za[g] = a;
        __syncthreads();
        if (g < 64) {
            float iv = za[g], fv = za[64 + g], cd = za[128 + g], ov = za[192 + g];
            c = fmaf(fv, c, iv * cd);
            float ca = (act == 0) ? fmaxf(c, 0.f) : tanhf_(c);
            float h = ov * ca;
            hs[g] = h;
            hr[t * 64 + g] = h;
        }
        __syncthreads();
        cur = nxt;
    }
}

// ---------------------------------------------------------------------------
// LSTM H=128, G=512 (keypoint layer 2, relu).
// ---------------------------------------------------------------------------
__global__ __launch_bounds__(512, 2) void lstm_h128(
    const float* __restrict__ xz, const float* __restrict__ Wh, float* __restrict__ hout) {
    int b = blockIdx.x;
    int g = threadIdx.x;
    float w[128];
#pragma unroll
    for (int k = 0; k < 128; k++) w[k] = Wh[k * 512 + g];

    __shared__ alignas(16) float hs[128];
    __shared__ float za[512];
    if (g < 128) hs[g] = 0.f;
    float c = 0.f;
    __syncthreads();

    const float* xzr = xz + (size_t)b * 64 * 512;
    float* hr = hout + (size_t)b * 64 * 128;
    bool isc = (g >= 256) && (g < 384);
    float cur = xzr[g];
    for (int t = 0; t < 64; t++) {
        float nxt = 0.f;
        if (t < 63) nxt = xzr[(t + 1) * 512 + g];
        float z0 = cur, z1 = 0.f, z2 = 0.f, z3 = 0.f;
#pragma unroll
        for (int kk = 0; kk < 32; kk++) {
            float4 h4 = *(const float4*)&hs[kk * 4];
            float a0 = fmaf(h4.x, w[kk * 4 + 0], fmaf(h4.y, w[kk * 4 + 1], 0.f));
            float a1 = fmaf(h4.z, w[kk * 4 + 2], fmaf(h4.w, w[kk * 4 + 3], 0.f));
            if ((kk & 1) == 0) { z0 += a0; z1 += a1; }
            else { z2 += a0; z3 += a1; }
        }
        float z = (z0 + z1) + (z2 + z3);
        float a = isc ? fmaxf(z, 0.f) : sigmoidf_(z);
        za[g] = a;
        __syncthreads();
        if (g < 128) {
            float iv = za[g], fv = za[128 + g], cd = za[256 + g], ov = za[384 + g];
            c = fmaf(fv, c, iv * cd);
            float h = ov * fmaxf(c, 0.f);
            hs[g] = h;
            hr[t * 128 + g] = h;
        }
        __syncthreads();
        cur = nxt;
    }
}

// ---------------------------------------------------------------------------
// GRU (reset_after), H=8, G=24. One wave per batch row, shuffle-based,
// no LDS / no barriers. Gate order z,r,h.
// ---------------------------------------------------------------------------
__global__ __launch_bounds__(64) void gru_kernel(
    const float* __restrict__ hsimg, const float* __restrict__ gWx,
    const float* __restrict__ gWh, const float* __restrict__ gb,
    float* __restrict__ glast) {
    int b = blockIdx.x;
    int qq = threadIdx.x;
    int col = (qq < 24) ? qq : 0;
    float wx[64], wh[8];
#pragma unroll
    for (int k = 0; k < 64; k++) wx[k] = gWx[k * 24 + col];
#pragma unroll
    for (int k = 0; k < 8; k++)  wh[k] = gWh[k * 24 + col];
    float b0 = gb[col], b1 = gb[24 + col];

    float hval = 0.f;                       // lanes 0..7 hold h state
    const float* hb = hsimg + (size_t)b * 64 * 64;
    for (int t = 0; t < 64; t++) {
        float s0 = b0, s1 = 0.f, s2 = 0.f, s3 = 0.f;
#pragma unroll
        for (int k = 0; k < 64; k += 4) {   // hb addresses are wave-uniform
            s0 = fmaf(hb[t * 64 + k + 0], wx[k + 0], s0);
            s1 = fmaf(hb[t * 64 + k + 1], wx[k + 1], s1);
            s2 = fmaf(hb[t * 64 + k + 2], wx[k + 2], s2);
            s3 = fmaf(hb[t * 64 + k + 3], wx[k + 3], s3);
        }
        float sx = (s0 + s1) + (s2 + s3);
        float sr = b1;
#pragma unroll
        for (int k = 0; k < 8; k++) sr = fmaf(__shfl(hval, k), wh[k], sr);
        // lanes 0..7 finalize (others compute garbage harmlessly)
        float xzz = __shfl(sx, qq),      rzz = __shfl(sr, qq);
        float xzr = __shfl(sx, 8 + qq),  rzr = __shfl(sr, 8 + qq);
        float xzh = __shfl(sx, 16 + qq), rzh = __shfl(sr, 16 + qq);
        float zz = sigmoidf_(xzz + rzz);
        float rv = sigmoidf_(xzr + rzr);
        float hc = tanhf_(xzh + rv * rzh);
        hval = zz * hval + (1.f - zz) * hc;
    }
    if (qq < 8) glast[b * 8 + qq] = hval;
}

// ---------------------------------------------------------------------------
// Dense heads + concat + final dense + softmax. 4 blocks x 64 rows.
// ---------------------------------------------------------------------------
__global__ __launch_bounds__(64) void final_head(
    const float* __restrict__ h3seq, const float* __restrict__ glast,
    const float* __restrict__ kD1w, const float* __restrict__ kD1b,
    const float* __restrict__ kD2w, const float* __restrict__ kD2b,
    const float* __restrict__ iDw,  const float* __restrict__ iDb,
    const float* __restrict__ fW,   const float* __restrict__ fb,
    float* __restrict__ outp) {
    int b = blockIdx.x * 64 + threadIdx.x;
    float h3[64];
#pragma unroll
    for (int k = 0; k < 64; k++) h3[k] = h3seq[((size_t)b * 64 + 63) * 64 + k];
    float d1[64];
#pragma unroll
    for (int j = 0; j < 64; j++) {
        float s = kD1b[j];
#pragma unroll
        for (int k = 0; k < 64; k++) s = fmaf(h3[k], kD1w[k * 64 + j], s);
        d1[j] = fmaxf(s, 0.f);
    }
    float d2[32];
#pragma unroll
    for (int j = 0; j < 32; j++) {
        float s = kD2b[j];
#pragma unroll
        for (int k = 0; k < 64; k++) s = fmaf(d1[k], kD2w[k * 32 + j], s);
        d2[j] = fmaxf(s, 0.f);
    }
    float gi[8];
#pragma unroll
    for (int k = 0; k < 8; k++) gi[k] = glast[b * 8 + k];
    float io[8];
#pragma unroll
    for (int j = 0; j < 8; j++) {
        float s = iDb[j];
#pragma unroll
        for (int k = 0; k < 8; k++) s = fmaf(gi[k], iDw[k * 8 + j], s);
        io[j] = fmaxf(s, 0.f);
    }
    float lg[10];
#pragma unroll
    for (int j = 0; j < 10; j++) {
        float s = fb[j];
#pragma unroll
        for (int k = 0; k < 8; k++)  s = fmaf(io[k], fW[k * 10 + j], s);
#pragma unroll
        for (int k = 0; k < 32; k++) s = fmaf(d2[k], fW[(8 + k) * 10 + j], s);
        lg[j] = s;
    }
    float mx = lg[0];
#pragma unroll
    for (int j = 1; j < 10; j++) mx = fmaxf(mx, lg[j]);
    float den = 0.f, ex[10];
#pragma unroll
    for (int j = 0; j < 10; j++) { ex[j] = __expf(lg[j] - mx); den += ex[j]; }
    float inv = 1.f / den;
#pragma unroll
    for (int j = 0; j < 10; j++) outp[b * 10 + j] = ex[j] * inv;
}

// ---------------------------------------------------------------------------
extern "C" void kernel_launch(void* const* d_in, const int* in_sizes, int n_in,
                              void* d_out, int out_size, void* d_ws, size_t ws_size,
                              hipStream_t stream) {
    const float* keypoint = (const float*)d_in[0];
    const float* img      = (const float*)d_in[1];
    const float* kW1x = (const float*)d_in[2];
    const float* kW1h = (const float*)d_in[3];
    const float* kb1  = (const float*)d_in[4];
    const float* kW2x = (const float*)d_in[5];
    const float* kW2h = (const float*)d_in[6];
    const float* kb2  = (const float*)d_in[7];
    const float* kW3x = (const float*)d_in[8];
    const float* kW3h = (const float*)d_in[9];
    const float* kb3  = (const float*)d_in[10];
    const float* kD1w = (const float*)d_in[11];
    const float* kD1b = (const float*)d_in[12];
    const float* kD2w = (const float*)d_in[13];
    const float* kD2b = (const float*)d_in[14];
    const float* iWx  = (const float*)d_in[15];
    const float* iWh  = (const float*)d_in[16];
    const float* ib   = (const float*)d_in[17];
    const float* gWx  = (const float*)d_in[18];
    const float* gWh  = (const float*)d_in[19];
    const float* gb   = (const float*)d_in[20];
    const float* iDw  = (const float*)d_in[21];
    const float* iDb  = (const float*)d_in[22];
    const float* fW   = (const float*)d_in[23];
    const float* fb   = (const float*)d_in[24];
    float* outp = (float*)d_out;

    char* ws = (char*)d_ws;
    const size_t MB16 = (size_t)16384 * 256 * 4;   // 16.78 MB
    // R1: xz1 partials -> later xz3 partials
    float* r1a = (float*)(ws);
    float* r1b = (float*)(ws + MB16);
    // R2: xz_img partials -> later xz2 (single, 33.55 MB)
    float* r2a = (float*)(ws + 2 * MB16);
    float* r2b = (float*)(ws + 3 * MB16);
    size_t off = 4 * MB16;
    float* h1seq = (float*)(ws + off); off += (size_t)16384 * 64 * 4;   // also h3seq
    float* h2seq = (float*)(ws + off); off += (size_t)16384 * 128 * 4;
    float* hsimg = (float*)(ws + off); off += (size_t)16384 * 64 * 4;
    float* glast = (float*)(ws + off); off += (size_t)256 * 8 * 4;
    unsigned short* w1h = (unsigned short*)(ws + off); off += (size_t)52 * 256 * 32 * 2;
    unsigned short* w1l = (unsigned short*)(ws + off); off += (size_t)52 * 256 * 32 * 2;
    unsigned short* wih = (unsigned short*)(ws + off); off += (size_t)64 * 256 * 32 * 2;
    unsigned short* wil = (unsigned short*)(ws + off); off += (size_t)64 * 256 * 32 * 2;
    unsigned short* w2h = (unsigned short*)(ws + off); off += (size_t)2 * 512 * 32 * 2;
    unsigned short* w2l = (unsigned short*)(ws + off); off += (size_t)2 * 512 * 32 * 2;
    unsigned short* w3h = (unsigned short*)(ws + off); off += (size_t)4 * 256 * 32 * 2;
    unsigned short* w3l = (unsigned short*)(ws + off); off += (size_t)4 * 256 * 32 * 2;
    float* xz2   = r2a;   // 33.55 MB spanning r2a+r2b (img partials consumed)
    float* h3seq = h1seq;

    // 1. pre-split projection weights
    split_all<<<124, 256, 0, stream>>>(kW1x, iWx, kW2x, kW3x,
                                       w1h, w1l, wih, wil, w2h, w2l, w3h, w3l);
    // 2. xz1 partials (split-K 2)
    gemm_rd<<<dim3(256, 1, 2), 256, 0, stream>>>(keypoint, w1h, w1l, kb1, r1a, r1b, 1662, 52, 256);
    // 3. xz_img partials (split-K 2)
    gemm_rd<<<dim3(256, 1, 2), 256, 0, stream>>>(img, wih, wil, ib, r2a, r2b, 2048, 64, 256);
    // 4. LSTM1 (relu) + img LSTM (tanh), fused
    lstm_h64<<<512, 256, 0, stream>>>(256, r1a, r1b, kW1h, h1seq, 0, r2a, r2b, iWh, hsimg, 1);
    // 5. xz2 = h1seq @ kW2x + kb2 (single-K, grid 512)
    gemm_rd<<<dim3(256, 2, 1), 256, 0, stream>>>(h1seq, w2h, w2l, kb2, xz2, xz2, 64, 2, 512);
    // 6. LSTM2 (relu)
    lstm_h128<<<256, 512, 0, stream>>>(xz2, kW2h, h2seq);
    // 7. xz3 partials (split-K 2) into R1 (xz1 consumed)
    gemm_rd<<<dim3(256, 1, 2), 256, 0, stream>>>(h2seq, w3h, w3l, kb3, r1a, r1b, 128, 4, 256);
    // 8. LSTM3 (relu)
    lstm_h64<<<256, 256, 0, stream>>>(256, r1a, r1b, kW3h, h3seq, 0, r1a, r1b, kW3h, h3seq, 0);
    // 9. GRU over img hidden seq
    gru_kernel<<<256, 64, 0, stream>>>(hsimg, gWx, gWh, gb, glast);
    // 10. heads + softmax
    final_head<<<4, 64, 0, stream>>>(h3seq, glast, kD1w, kD1b, kD2w, kD2b,
                                     iDw, iDb, fW, fb, outp);
    (void)in_sizes; (void)n_in; (void)out_size; (void)ws_size;
}

// Round 3
// 700.309 us; speedup vs baseline: 1.2441x; 1.0776x over previous
//
#include <hip/hip_runtime.h>

// ---------------------------------------------------------------------------
// CombinedModel: 3x relu-LSTM (keypoint) + tanh-LSTM + GRU (img) + heads.
//   GEMMs: split-bf16 MFMA (hi/lo, 3 MFMA per tile-pair ~= fp32 accuracy).
//     BK=64 group pipeline: A prefetched to REGISTERS right after the barrier
//     (so the barrier's vmcnt(0) drain never blocks them), converted+ds_written
//     only after the group's 96 MFMAs -> HBM latency hidden under MFMA.
//     B register-direct from pre-split global [kt][n][32].
//   Recurrences: block per batch row, weights in VGPRs, 4 indep FMA chains,
//     xz prefetch, fast tanh. GRU: 1 wave/row, register h-seq + shuffle.
// ---------------------------------------------------------------------------

typedef short bf16x8 __attribute__((ext_vector_type(8)));
typedef float f32x4 __attribute__((ext_vector_type(4)));

__device__ __forceinline__ unsigned f2bf(float x) {
    unsigned u = __float_as_uint(x);
    return (u + 0x7FFFu + ((u >> 16) & 1u)) >> 16;   // RNE; inputs finite
}
__device__ __forceinline__ float bf2f(unsigned b) { return __uint_as_float(b << 16); }
__device__ __forceinline__ float sigmoidf_(float x) { return 1.f / (1.f + __expf(-x)); }
__device__ __forceinline__ float tanhf_(float x) {
    float e = __expf(2.f * x);
    return 1.f - 2.f / (e + 1.f);
}

// ---------------------------------------------------------------------------
// Weight pre-split: W[K,N] f32 -> bf16 hi/lo, blocked [kt][n][32].
// ---------------------------------------------------------------------------
template<int K, int N>
__device__ __forceinline__ void split_w(const float* __restrict__ W,
                                        unsigned short* __restrict__ hi,
                                        unsigned short* __restrict__ lo, int item) {
    int kt = item / N;
    int n  = item % N;
    unsigned uh[16], ul[16];
#pragma unroll
    for (int p = 0; p < 16; p++) {
        unsigned h2[2], l2[2];
#pragma unroll
        for (int e = 0; e < 2; e++) {
            int k = kt * 32 + p * 2 + e;
            float x = (k < K) ? W[(size_t)k * N + n] : 0.f;
            unsigned hb = f2bf(x);
            h2[e] = hb;
            l2[e] = f2bf(x - bf2f(hb));
        }
        uh[p] = h2[0] | (h2[1] << 16);
        ul[p] = l2[0] | (l2[1] << 16);
    }
    size_t off = (size_t)(kt * N + n) * 32;
    uint4* dh = (uint4*)(hi + off);
    uint4* dl = (uint4*)(lo + off);
#pragma unroll
    for (int c = 0; c < 4; c++) {
        uint4 v; v.x = uh[c*4]; v.y = uh[c*4+1]; v.z = uh[c*4+2]; v.w = uh[c*4+3];
        dh[c] = v;
        uint4 u; u.x = ul[c*4]; u.y = ul[c*4+1]; u.z = ul[c*4+2]; u.w = ul[c*4+3];
        dl[c] = u;
    }
}

__global__ __launch_bounds__(256) void split_all(
    const float* kW1x, const float* iWx, const float* kW2x, const float* kW3x,
    unsigned short* w1h, unsigned short* w1l, unsigned short* wih, unsigned short* wil,
    unsigned short* w2h, unsigned short* w2l, unsigned short* w3h, unsigned short* w3l) {
    int wid = blockIdx.x * 256 + threadIdx.x;
    if (wid < 13312)       split_w<1662, 256>(kW1x, w1h, w1l, wid);
    else if (wid < 29696)  split_w<2048, 256>(iWx,  wih, wil, wid - 13312);
    else if (wid < 30720)  split_w<64,   512>(kW2x, w2h, w2l, wid - 29696);
    else if (wid < 31744)  split_w<128,  256>(kW3x, w3h, w3l, wid - 30720);
}

// ---------------------------------------------------------------------------
// GEMM: out = A[16384,Kreal] @ W + bias.  Block 256 thr (4 waves), tile 64x256,
// BK=64 (2 kt-subtiles) per barrier interval, register A-prefetch.
// grid = (M/64, Nfull/256, ksplit).  Requires (Kt/ksplit) even.
// ---------------------------------------------------------------------------
__global__ __launch_bounds__(256, 2) void gemm_rd(
    const float* __restrict__ A, const unsigned short* __restrict__ Bhi,
    const unsigned short* __restrict__ Blo, const float* __restrict__ bias,
    float* __restrict__ out0, float* __restrict__ out1,
    int Kreal, int Kt, int Nfull) {
    const int m0  = blockIdx.x * 64;
    const int n0  = blockIdx.y * 256;
    const int ks  = blockIdx.z;
    const int nks = gridDim.z;
    const int ktChunk = Kt / nks;            // even by construction
    const int kt0 = ks * ktChunk;
    const int G   = ktChunk / 2;             // 64-wide k-groups
    const int tid = threadIdx.x;
    const int lane = tid & 63;
    const int wv   = tid >> 6;
    const int l15  = lane & 15;
    const int q    = lane >> 4;
    const int row  = tid >> 2;               // staging: 64 rows x 4 chunks
    const int kc   = tid & 3;                // 16 k per chunk

    __shared__ unsigned short Ah[2][2][64 * 40], Al[2][2][64 * 40];  // 40 KB

    f32x4 acc[4][4];
#pragma unroll
    for (int i = 0; i < 4; i++)
#pragma unroll
        for (int j = 0; j < 4; j++) acc[i][j] = (f32x4){0.f, 0.f, 0.f, 0.f};

    // ---- load group g's A slice (16 floats) into registers ----
    auto loadA = [&](int g, float* r) {
        int kb = (kt0 + 2 * g) * 32 + kc * 16;
        const float* ap = A + (size_t)(m0 + row) * Kreal + kb;
#pragma unroll
        for (int j = 0; j < 8; j++) {
            int gk = kb + 2 * j;
            if (gk + 2 <= Kreal) {
                float2 p = *(const float2*)(ap + 2 * j);
                r[2*j] = p.x; r[2*j+1] = p.y;
            } else {
                r[2*j]   = (gk < Kreal) ? ap[2*j] : 0.f;
                r[2*j+1] = 0.f;
            }
        }
    };
    // ---- convert regs -> hi/lo bf16, write to LDS buffer ----
    auto writeA = [&](int buf, const float* r) {
        int sub = kc >> 1;
        int kk0 = (kc & 1) * 16;
        unsigned ph[8], pl[8];
#pragma unroll
        for (int p = 0; p < 8; p++) {
            unsigned h0 = f2bf(r[2*p]),   h1 = f2bf(r[2*p+1]);
            unsigned l0 = f2bf(r[2*p] - bf2f(h0));
            unsigned l1 = f2bf(r[2*p+1] - bf2f(h1));
            ph[p] = h0 | (h1 << 16);
            pl[p] = l0 | (l1 << 16);
        }
        uint4* dh = (uint4*)&Ah[buf][sub][row * 40 + kk0];
        uint4* dl = (uint4*)&Al[buf][sub][row * 40 + kk0];
        uint4 v0; v0.x = ph[0]; v0.y = ph[1]; v0.z = ph[2]; v0.w = ph[3];
        uint4 v1; v1.x = ph[4]; v1.y = ph[5]; v1.z = ph[6]; v1.w = ph[7];
        dh[0] = v0; dh[1] = v1;
        uint4 u0; u0.x = pl[0]; u0.y = pl[1]; u0.z = pl[2]; u0.w = pl[3];
        uint4 u1; u1.x = pl[4]; u1.y = pl[5]; u1.z = pl[6]; u1.w = pl[7];
        dl[0] = u0; dl[1] = u1;
    };

    float r0[16];
    loadA(0, r0);
    writeA(0, r0);

    for (int g = 0; g < G; g++) {
        int buf = g & 1;
        __syncthreads();                     // bufs[buf] ready for all waves
        float rn[16];
        if (g + 1 < G) loadA(g + 1, rn);     // issued AFTER barrier; used after MFMA
#pragma unroll
        for (int sub = 0; sub < 2; sub++) {
            int ktg = kt0 + 2 * g + sub;
            bf16x8 bh[4], bl[4];
#pragma unroll
            for (int nt = 0; nt < 4; nt++) {
                size_t boff = ((size_t)ktg * Nfull + n0 + wv * 64 + nt * 16 + l15) * 32 + q * 8;
                bh[nt] = *(const bf16x8*)(Bhi + boff);
                bl[nt] = *(const bf16x8*)(Blo + boff);
            }
#pragma unroll
            for (int mt = 0; mt < 4; mt++) {
                int o = (mt * 16 + l15) * 40 + q * 8;
                bf16x8 ah = *(const bf16x8*)&Ah[buf][sub][o];
                bf16x8 al = *(const bf16x8*)&Al[buf][sub][o];
#pragma unroll
                for (int nt = 0; nt < 4; nt++) {
                    acc[mt][nt] = __builtin_amdgcn_mfma_f32_16x16x32_bf16(ah, bh[nt], acc[mt][nt], 0, 0, 0);
                    acc[mt][nt] = __builtin_amdgcn_mfma_f32_16x16x32_bf16(ah, bl[nt], acc[mt][nt], 0, 0, 0);
                    acc[mt][nt] = __builtin_amdgcn_mfma_f32_16x16x32_bf16(al, bh[nt], acc[mt][nt], 0, 0, 0);
                }
            }
        }
        if (g + 1 < G) writeA(buf ^ 1, rn);  // vmcnt wait lands here, post-MFMA
    }
    float* op = (ks == 0) ? out0 : out1;
#pragma unroll
    for (int nt = 0; nt < 4; nt++) {
        int gcol = n0 + wv * 64 + nt * 16 + l15;
        float bv = (ks == 0) ? bias[gcol] : 0.f;
#pragma unroll
        for (int mt = 0; mt < 4; mt++)
#pragma unroll
            for (int r = 0; r < 4; r++) {
                int grow = m0 + mt * 16 + q * 4 + r;
                op[(size_t)grow * Nfull + gcol] = acc[mt][nt][r] + bv;
            }
    }
}

// ---------------------------------------------------------------------------
// LSTM H=64, G=256 (dual-config). xz = sum of two partials (p1 nullable).
// 4 independent 16-deep FMA chains (64 FMAs total, not 96).
// ---------------------------------------------------------------------------
__global__ __launch_bounds__(256) void lstm_h64(
    int nA,
    const float* __restrict__ xA0, const float* __restrict__ xA1,
    const float* __restrict__ WhA, float* __restrict__ hA, int actA,
    const float* __restrict__ xB0, const float* __restrict__ xB1,
    const float* __restrict__ WhB, float* __restrict__ hB, int actB) {
    int bid = blockIdx.x;
    bool sec = bid >= nA;
    int b = sec ? bid - nA : bid;
    const float* x0 = sec ? xB0 : xA0;
    const float* x1 = sec ? xB1 : xA1;
    const float* Wh = sec ? WhB : WhA;
    float* hout     = sec ? hB  : hA;
    int act         = sec ? actB : actA;
    bool has1 = (x1 != nullptr);

    int g = threadIdx.x;
    float w[64];
#pragma unroll
    for (int k = 0; k < 64; k++) w[k] = Wh[k * 256 + g];

    __shared__ alignas(16) float hs[64];
    __shared__ float za[256];
    if (g < 64) hs[g] = 0.f;
    float c = 0.f;
    __syncthreads();

    const float* x0r = x0 + (size_t)b * 64 * 256;
    const float* x1r = has1 ? x1 + (size_t)b * 64 * 256 : x0r;
    float* hr = hout + (size_t)b * 64 * 64;
    bool isc = (g >= 128) && (g < 192);
    float cur = x0r[g] + (has1 ? x1r[g] : 0.f);
    for (int t = 0; t < 64; t++) {
        float nxt = 0.f;
        if (t < 63) {
            nxt = x0r[(t + 1) * 256 + g];
            if (has1) nxt += x1r[(t + 1) * 256 + g];
        }
        float z0 = cur, z1 = 0.f, z2 = 0.f, z3 = 0.f;
#pragma unroll
        for (int kk = 0; kk < 16; kk++) {
            float4 h4 = *(const float4*)&hs[kk * 4];
            z0 = fmaf(h4.x, w[kk * 4 + 0], z0);
            z1 = fmaf(h4.y, w[kk * 4 + 1], z1);
            z2 = fmaf(h4.z, w[kk * 4 + 2], z2);
            z3 = fmaf(h4.w, w[kk * 4 + 3], z3);
        }
        float z = (z0 + z1) + (z2 + z3);
        float a;
        if (isc) a = (act == 0) ? fmaxf(z, 0.f) : tanhf_(z);
        else     a = sigmoidf_(z);
        za[g] = a;
        __syncthreads();
        if (g < 64) {
            float iv = za[g], fv = za[64 + g], cd = za[128 + g], ov = za[192 + g];
            c = fmaf(fv, c, iv * cd);
            float ca = (act == 0) ? fmaxf(c, 0.f) : tanhf_(c);
            float h = ov * ca;
            hs[g] = h;
            hr[t * 64 + g] = h;
        }
        __syncthreads();
        cur = nxt;
    }
}

// ---------------------------------------------------------------------------
// LSTM H=128, G=512 (keypoint layer 2, relu).
// ---------------------------------------------------------------------------
__global__ __launch_bounds__(512, 2) void lstm_h128(
    const float* __restrict__ xz, const float* __restrict__ Wh, float* __restrict__ hout) {
    int b = blockIdx.x;
    int g = threadIdx.x;
    float w[128];
#pragma unroll
    for (int k = 0; k < 128; k++) w[k] = Wh[k * 512 + g];

    __shared__ alignas(16) float hs[128];
    __shared__ float za[512];
    if (g < 128) hs[g] = 0.f;
    float c = 0.f;
    __syncthreads();

    const float* xzr = xz + (size_t)b * 64 * 512;
    float* hr = hout + (size_t)b * 64 * 128;
    bool isc = (g >= 256) && (g < 384);
    float cur = xzr[g];
    for (int t = 0; t < 64; t++) {
        float nxt = 0.f;
        if (t < 63) nxt = xzr[(t + 1) * 512 + g];
        float z0 = cur, z1 = 0.f, z2 = 0.f, z3 = 0.f;
#pragma unroll
        for (int kk = 0; kk < 32; kk++) {
            float4 h4 = *(const float4*)&hs[kk * 4];
            z0 = fmaf(h4.x, w[kk * 4 + 0], z0);
            z1 = fmaf(h4.y, w[kk * 4 + 1], z1);
            z2 = fmaf(h4.z, w[kk * 4 + 2], z2);
            z3 = fmaf(h4.w, w[kk * 4 + 3], z3);
        }
        float z = (z0 + z1) + (z2 + z3);
        float a = isc ? fmaxf(z, 0.f) : sigmoidf_(z);
        za[g] = a;
        __syncthreads();
        if (g < 128) {
            float iv = za[g], fv = za[128 + g], cd = za[256 + g], ov = za[384 + g];
            c = fmaf(fv, c, iv * cd);
            float h = ov * fmaxf(c, 0.f);
            hs[g] = h;
            hr[t * 128 + g] = h;
        }
        __syncthreads();
        cur = nxt;
    }
}

// ---------------------------------------------------------------------------
// GRU (reset_after), H=8, G=24. One wave per batch row. h-row of the img LSTM
// is loaded coalesced (lane q holds h[t][q]) and broadcast via shuffles ->
// zero per-step memory latency. Gate order z,r,h.
// ---------------------------------------------------------------------------
__global__ __launch_bounds__(64) void gru_kernel(
    const float* __restrict__ hsimg, const float* __restrict__ gWx,
    const float* __restrict__ gWh, const float* __restrict__ gb,
    float* __restrict__ glast) {
    int b = blockIdx.x;
    int qq = threadIdx.x;
    int col = (qq < 24) ? qq : 0;
    float wx[64], wh[8];
#pragma unroll
    for (int k = 0; k < 64; k++) wx[k] = gWx[k * 24 + col];
#pragma unroll
    for (int k = 0; k < 8; k++)  wh[k] = gWh[k * 24 + col];
    float b0 = gb[col], b1 = gb[24 + col];

    float hval = 0.f;                       // lanes 0..7 hold h state
    const float* hb = hsimg + (size_t)b * 64 * 64;
    float cur = hb[qq];                     // h[0][qq], coalesced
    for (int t = 0; t < 64; t++) {
        float nxt = (t < 63) ? hb[(t + 1) * 64 + qq] : 0.f;
        float s0 = b0, s1 = 0.f, s2 = 0.f, s3 = 0.f;
#pragma unroll
        for (int k = 0; k < 64; k += 4) {
            s0 = fmaf(__shfl(cur, k + 0), wx[k + 0], s0);
            s1 = fmaf(__shfl(cur, k + 1), wx[k + 1], s1);
            s2 = fmaf(__shfl(cur, k + 2), wx[k + 2], s2);
            s3 = fmaf(__shfl(cur, k + 3), wx[k + 3], s3);
        }
        float sx = (s0 + s1) + (s2 + s3);
        float sr = b1;
#pragma unroll
        for (int k = 0; k < 8; k++) sr = fmaf(__shfl(hval, k), wh[k], sr);
        float xzz = __shfl(sx, qq),      rzz = __shfl(sr, qq);
        float xzr = __shfl(sx, 8 + qq),  rzr = __shfl(sr, 8 + qq);
        float xzh = __shfl(sx, 16 + qq), rzh = __shfl(sr, 16 + qq);
        float zz = sigmoidf_(xzz + rzz);
        float rv = sigmoidf_(xzr + rzr);
        float hc = tanhf_(xzh + rv * rzh);
        hval = zz * hval + (1.f - zz) * hc;
        cur = nxt;
    }
    if (qq < 8) glast[b * 8 + qq] = hval;
}

// ---------------------------------------------------------------------------
// Dense heads + concat + final dense + softmax. 4 blocks x 64 rows.
// ---------------------------------------------------------------------------
__global__ __launch_bounds__(64) void final_head(
    const float* __restrict__ h3seq, const float* __restrict__ glast,
    const float* __restrict__ kD1w, const float* __restrict__ kD1b,
    const float* __restrict__ kD2w, const float* __restrict__ kD2b,
    const float* __restrict__ iDw,  const float* __restrict__ iDb,
    const float* __restrict__ fW,   const float* __restrict__ fb,
    float* __restrict__ outp) {
    int b = blockIdx.x * 64 + threadIdx.x;
    float h3[64];
#pragma unroll
    for (int k = 0; k < 64; k++) h3[k] = h3seq[((size_t)b * 64 + 63) * 64 + k];
    float d1[64];
#pragma unroll
    for (int j = 0; j < 64; j++) {
        float s = kD1b[j];
#pragma unroll
        for (int k = 0; k < 64; k++) s = fmaf(h3[k], kD1w[k * 64 + j], s);
        d1[j] = fmaxf(s, 0.f);
    }
    float d2[32];
#pragma unroll
    for (int j = 0; j < 32; j++) {
        float s = kD2b[j];
#pragma unroll
        for (int k = 0; k < 64; k++) s = fmaf(d1[k], kD2w[k * 32 + j], s);
        d2[j] = fmaxf(s, 0.f);
    }
    float gi[8];
#pragma unroll
    for (int k = 0; k < 8; k++) gi[k] = glast[b * 8 + k];
    float io[8];
#pragma unroll
    for (int j = 0; j < 8; j++) {
        float s = iDb[j];
#pragma unroll
        for (int k = 0; k < 8; k++) s = fmaf(gi[k], iDw[k * 8 + j], s);
        io[j] = fmaxf(s, 0.f);
    }
    float lg[10];
#pragma unroll
    for (int j = 0; j < 10; j++) {
        float s = fb[j];
#pragma unroll
        for (int k = 0; k < 8; k++)  s = fmaf(io[k], fW[k * 10 + j], s);
#pragma unroll
        for (int k = 0; k < 32; k++) s = fmaf(d2[k], fW[(8 + k) * 10 + j], s);
        lg[j] = s;
    }
    float mx = lg[0];
#pragma unroll
    for (int j = 1; j < 10; j++) mx = fmaxf(mx, lg[j]);
    float den = 0.f, ex[10];
#pragma unroll
    for (int j = 0; j < 10; j++) { ex[j] = __expf(lg[j] - mx); den += ex[j]; }
    float inv = 1.f / den;
#pragma unroll
    for (int j = 0; j < 10; j++) outp[b * 10 + j] = ex[j] * inv;
}

// ---------------------------------------------------------------------------
extern "C" void kernel_launch(void* const* d_in, const int* in_sizes, int n_in,
                              void* d_out, int out_size, void* d_ws, size_t ws_size,
                              hipStream_t stream) {
    const float* keypoint = (const float*)d_in[0];
    const float* img      = (const float*)d_in[1];
    const float* kW1x = (const float*)d_in[2];
    const float* kW1h = (const float*)d_in[3];
    const float* kb1  = (const float*)d_in[4];
    const float* kW2x = (const float*)d_in[5];
    const float* kW2h = (const float*)d_in[6];
    const float* kb2  = (const float*)d_in[7];
    const float* kW3x = (const float*)d_in[8];
    const float* kW3h = (const float*)d_in[9];
    const float* kb3  = (const float*)d_in[10];
    const float* kD1w = (const float*)d_in[11];
    const float* kD1b = (const float*)d_in[12];
    const float* kD2w = (const float*)d_in[13];
    const float* kD2b = (const float*)d_in[14];
    const float* iWx  = (const float*)d_in[15];
    const float* iWh  = (const float*)d_in[16];
    const float* ib   = (const float*)d_in[17];
    const float* gWx  = (const float*)d_in[18];
    const float* gWh  = (const float*)d_in[19];
    const float* gb   = (const float*)d_in[20];
    const float* iDw  = (const float*)d_in[21];
    const float* iDb  = (const float*)d_in[22];
    const float* fW   = (const float*)d_in[23];
    const float* fb   = (const float*)d_in[24];
    float* outp = (float*)d_out;

    char* ws = (char*)d_ws;
    const size_t MB16 = (size_t)16384 * 256 * 4;
    float* r1a = (float*)(ws);
    float* r1b = (float*)(ws + MB16);
    float* r2a = (float*)(ws + 2 * MB16);
    float* r2b = (float*)(ws + 3 * MB16);
    size_t off = 4 * MB16;
    float* h1seq = (float*)(ws + off); off += (size_t)16384 * 64 * 4;
    float* h2seq = (float*)(ws + off); off += (size_t)16384 * 128 * 4;
    float* hsimg = (float*)(ws + off); off += (size_t)16384 * 64 * 4;
    float* glast = (float*)(ws + off); off += (size_t)256 * 8 * 4;
    unsigned short* w1h = (unsigned short*)(ws + off); off += (size_t)52 * 256 * 32 * 2;
    unsigned short* w1l = (unsigned short*)(ws + off); off += (size_t)52 * 256 * 32 * 2;
    unsigned short* wih = (unsigned short*)(ws + off); off += (size_t)64 * 256 * 32 * 2;
    unsigned short* wil = (unsigned short*)(ws + off); off += (size_t)64 * 256 * 32 * 2;
    unsigned short* w2h = (unsigned short*)(ws + off); off += (size_t)2 * 512 * 32 * 2;
    unsigned short* w2l = (unsigned short*)(ws + off); off += (size_t)2 * 512 * 32 * 2;
    unsigned short* w3h = (unsigned short*)(ws + off); off += (size_t)4 * 256 * 32 * 2;
    unsigned short* w3l = (unsigned short*)(ws + off); off += (size_t)4 * 256 * 32 * 2;
    float* xz2   = r2a;   // spans r2a+r2b after img partials consumed
    float* h3seq = h1seq;

    split_all<<<124, 256, 0, stream>>>(kW1x, iWx, kW2x, kW3x,
                                       w1h, w1l, wih, wil, w2h, w2l, w3h, w3l);
    // xz1 partials: Kt=52, ks=2 -> chunks 26 (even)
    gemm_rd<<<dim3(256, 1, 2), 256, 0, stream>>>(keypoint, w1h, w1l, kb1, r1a, r1b, 1662, 52, 256);
    // xz_img partials: Kt=64, ks=2 -> chunks 32
    gemm_rd<<<dim3(256, 1, 2), 256, 0, stream>>>(img, wih, wil, ib, r2a, r2b, 2048, 64, 256);
    lstm_h64<<<512, 256, 0, stream>>>(256, r1a, r1b, kW1h, h1seq, 0, r2a, r2b, iWh, hsimg, 1);
    // xz2: Kt=2, ks=1 -> 1 group
    gemm_rd<<<dim3(256, 2, 1), 256, 0, stream>>>(h1seq, w2h, w2l, kb2, xz2, xz2, 64, 2, 512);
    lstm_h128<<<256, 512, 0, stream>>>(xz2, kW2h, h2seq);
    // xz3: Kt=4, ks=2 -> chunks 2
    gemm_rd<<<dim3(256, 1, 2), 256, 0, stream>>>(h2seq, w3h, w3l, kb3, r1a, r1b, 128, 4, 256);
    lstm_h64<<<256, 256, 0, stream>>>(256, r1a, r1b, kW3h, h3seq, 0, r1a, r1b, kW3h, h3seq, 0);
    gru_kernel<<<256, 64, 0, stream>>>(hsimg, gWx, gWh, gb, glast);
    final_head<<<4, 64, 0, stream>>>(h3seq, glast, kD1w, kD1b, kD2w, kD2b,
                                     iDw, iDb, fW, fb, outp);
    (void)in_sizes; (void)n_in; (void)out_size; (void)ws_size;
}